// Round 1
// baseline (875.322 us; speedup 1.0000x reference)
//
#include <hip/hip_runtime.h>
#include <math.h>

#define NB 8
#define NC 64
#define NN 4096
#define NM 8

// ---------------------------------------------------------------------------
// Kernel 1: 1x1-conv projections.  x:[B,C,N] -> q:[B,N,8], k:[B,N,8], v:[B,N,64]
// Block: 256 threads handles one (b, 64-pixel) tile; x tile staged in LDS.
// ---------------------------------------------------------------------------
__global__ __launch_bounds__(256) void proj_kernel(
    const float* __restrict__ x,
    const float* __restrict__ wq, const float* __restrict__ bq,
    const float* __restrict__ wk, const float* __restrict__ bk,
    const float* __restrict__ wv, const float* __restrict__ bv,
    float* __restrict__ qo, float* __restrict__ ko, float* __restrict__ vo)
{
    const int b = blockIdx.x;
    const int n0 = blockIdx.y * 64;
    const int tid = threadIdx.x;

    __shared__ float xs[64][65];   // [c][n], +1 pad

    const float* xb = x + (size_t)b * NC * NN;
#pragma unroll
    for (int rep = 0; rep < 16; ++rep) {
        int idx = rep * 256 + tid;
        int c = idx >> 6, n = idx & 63;
        xs[c][n] = xb[(size_t)c * NN + n0 + n];   // coalesced along n
    }
    __syncthreads();

    const int n = tid & 63;
    const int rb = tid >> 6;   // 0..3  (wave-uniform)

    // q and k rows: rb and rb+4
#pragma unroll
    for (int t = 0; t < 2; ++t) {
        int r = rb + 4 * t;
        float aq = bq[r], ak = bk[r];
#pragma unroll
        for (int c = 0; c < 64; ++c) {
            float xv = xs[c][n];
            aq = fmaf(wq[r * 64 + c], xv, aq);
            ak = fmaf(wk[r * 64 + c], xv, ak);
        }
        qo[((size_t)b * NN + n0 + n) * NM + r] = aq;
        ko[((size_t)b * NN + n0 + n) * NM + r] = ak;
    }
    // v rows: rb + 4*s
#pragma unroll
    for (int s = 0; s < 16; ++s) {
        int r = rb + 4 * s;
        float av = bv[r];
#pragma unroll
        for (int c = 0; c < 64; ++c) av = fmaf(wv[r * 64 + c], xs[c][n], av);
        vo[((size_t)b * NN + n0 + n) * NC + r] = av;
    }
}

// ---------------------------------------------------------------------------
// Kernel 2: flash attention partials.  One thread = one query.
// Grid: (B, N/256, JS).  Each block covers j in [s*N/JS, (s+1)*N/JS).
// Partials: po [B,JS,C,N], pm/pl [B,JS,N]  (N-contiguous => coalesced).
// ---------------------------------------------------------------------------
__global__ __launch_bounds__(256) void attn_kernel(
    const float* __restrict__ qo, const float* __restrict__ ko,
    const float* __restrict__ vo,
    float* __restrict__ po, float* __restrict__ pm, float* __restrict__ pl,
    int JS)
{
    const int b = blockIdx.x;
    const int tid = threadIdx.x;
    const int i = blockIdx.y * 256 + tid;
    const int s = blockIdx.z;
    const int jlen = NN / JS;
    const int j0base = s * jlen;

    __shared__ float  ks[64][8];
    __shared__ float4 vs4[64][16];   // [j][c/4]

    float q[8];
    {
        const float4* q4 = (const float4*)(qo + ((size_t)b * NN + i) * NM);
        float4 a = q4[0], bb = q4[1];
        q[0] = a.x; q[1] = a.y; q[2] = a.z; q[3] = a.w;
        q[4] = bb.x; q[5] = bb.y; q[6] = bb.z; q[7] = bb.w;
    }

    float mx = -1e30f, l = 0.f;
    float4 o[16];
#pragma unroll
    for (int t = 0; t < 16; ++t) o[t] = make_float4(0.f, 0.f, 0.f, 0.f);

    for (int jt = 0; jt < jlen; jt += 64) {
        const int j0 = j0base + jt;
        __syncthreads();   // previous tile's readers done
        {
            const float* kb = ko + ((size_t)b * NN + j0) * NM;
            ((float*)ks)[tid]       = kb[tid];
            ((float*)ks)[tid + 256] = kb[tid + 256];
            const float4* vb4 = (const float4*)(vo + ((size_t)b * NN + j0) * NC);
            float4* vsf = (float4*)vs4;
#pragma unroll
            for (int r = 0; r < 4; ++r) vsf[r * 256 + tid] = vb4[r * 256 + tid];
        }
        __syncthreads();

        // pass 1: tile max
        float tmax = -1e30f;
#pragma unroll 8
        for (int j = 0; j < 64; ++j) {
            float sc = q[0] * ks[j][0] + q[1] * ks[j][1] + q[2] * ks[j][2] + q[3] * ks[j][3]
                     + q[4] * ks[j][4] + q[5] * ks[j][5] + q[6] * ks[j][6] + q[7] * ks[j][7];
            tmax = fmaxf(tmax, sc);
        }
        float mnew = fmaxf(mx, tmax);
        float alpha = __expf(mx - mnew);
        l *= alpha;
#pragma unroll
        for (int t = 0; t < 16; ++t) {
            o[t].x *= alpha; o[t].y *= alpha; o[t].z *= alpha; o[t].w *= alpha;
        }
        // pass 2: exp + accumulate
        for (int j = 0; j < 64; ++j) {
            float sc = q[0] * ks[j][0] + q[1] * ks[j][1] + q[2] * ks[j][2] + q[3] * ks[j][3]
                     + q[4] * ks[j][4] + q[5] * ks[j][5] + q[6] * ks[j][6] + q[7] * ks[j][7];
            float p = __expf(sc - mnew);
            l += p;
#pragma unroll
            for (int t = 0; t < 16; ++t) {
                float4 vv = vs4[j][t];
                o[t].x = fmaf(p, vv.x, o[t].x);
                o[t].y = fmaf(p, vv.y, o[t].y);
                o[t].z = fmaf(p, vv.z, o[t].z);
                o[t].w = fmaf(p, vv.w, o[t].w);
            }
        }
        mx = mnew;
    }

    float* pob = po + ((size_t)b * JS + s) * NC * NN + i;
#pragma unroll
    for (int t = 0; t < 16; ++t) {
        pob[(size_t)(4 * t + 0) * NN] = o[t].x;
        pob[(size_t)(4 * t + 1) * NN] = o[t].y;
        pob[(size_t)(4 * t + 2) * NN] = o[t].z;
        pob[(size_t)(4 * t + 3) * NN] = o[t].w;
    }
    pm[((size_t)b * JS + s) * NN + i] = mx;
    pl[((size_t)b * JS + s) * NN + i] = l;
}

// ---------------------------------------------------------------------------
// Kernel 3: combine partials, residual + gamma, write [B,C,N] output.
// ---------------------------------------------------------------------------
__global__ __launch_bounds__(256) void combine_kernel(
    const float* __restrict__ x, const float* __restrict__ gamma,
    const float* __restrict__ po, const float* __restrict__ pm,
    const float* __restrict__ pl, float* __restrict__ out, int JS)
{
    const int b = blockIdx.x;
    const int i = blockIdx.y * 256 + threadIdx.x;

    float M = -1e30f;
    for (int s = 0; s < JS; ++s) M = fmaxf(M, pm[((size_t)b * JS + s) * NN + i]);
    float es[8];
    float L = 0.f;
    for (int s = 0; s < JS; ++s) {
        float e = __expf(pm[((size_t)b * JS + s) * NN + i] - M);
        es[s] = e;
        L = fmaf(e, pl[((size_t)b * JS + s) * NN + i], L);
    }
    const float g = gamma[0];
    const float invL = 1.f / L;
#pragma unroll 4
    for (int c = 0; c < 64; ++c) {
        float acc = 0.f;
        for (int s = 0; s < JS; ++s)
            acc = fmaf(es[s], po[(((size_t)b * JS + s) * NC + c) * NN + i], acc);
        out[((size_t)b * NC + c) * NN + i] =
            x[((size_t)b * NC + c) * NN + i] + g * acc * invL;
    }
}

// ---------------------------------------------------------------------------
extern "C" void kernel_launch(void* const* d_in, const int* in_sizes, int n_in,
                              void* d_out, int out_size, void* d_ws, size_t ws_size,
                              hipStream_t stream) {
    const float* x     = (const float*)d_in[0];
    const float* wq    = (const float*)d_in[1];
    const float* bq    = (const float*)d_in[2];
    const float* wk    = (const float*)d_in[3];
    const float* bk    = (const float*)d_in[4];
    const float* wv    = (const float*)d_in[5];
    const float* bv    = (const float*)d_in[6];
    const float* gamma = (const float*)d_in[7];
    float* out = (float*)d_out;
    float* ws  = (float*)d_ws;

    size_t off = 0;
    float* qo = ws + off; off += (size_t)NB * NN * NM;
    float* ko = ws + off; off += (size_t)NB * NN * NM;
    float* vo = ws + off; off += (size_t)NB * NN * NC;

    int JS = 8;
    while (JS > 1) {
        size_t need = (off + (size_t)JS * ((size_t)NB * NN * 2 + (size_t)NB * NN * NC))
                      * sizeof(float);
        if (need <= ws_size) break;
        JS >>= 1;
    }
    float* pm = ws + off; off += (size_t)NB * JS * NN;
    float* pl = ws + off; off += (size_t)NB * JS * NN;
    float* po = ws + off; off += (size_t)NB * JS * NC * NN;

    proj_kernel<<<dim3(NB, NN / 64), 256, 0, stream>>>(x, wq, bq, wk, bk, wv, bv,
                                                       qo, ko, vo);
    attn_kernel<<<dim3(NB, NN / 256, JS), 256, 0, stream>>>(qo, ko, vo, po, pm, pl, JS);
    combine_kernel<<<dim3(NB, NN / 256), 256, 0, stream>>>(x, gamma, po, pm, pl, out, JS);
}

// Round 2
// 234.444 us; speedup vs baseline: 3.7336x; 3.7336x over previous
//
#include <hip/hip_runtime.h>
#include <math.h>

#define NB 8
#define NC 64
#define NN 4096
#define NM 8

typedef __attribute__((ext_vector_type(8))) short short8;
typedef __attribute__((ext_vector_type(4))) float float4v;

__device__ inline unsigned short f2bf(float f) {
    unsigned int u = __builtin_bit_cast(unsigned int, f);
    unsigned int r = (u + 0x7FFFu + ((u >> 16) & 1u)) >> 16;
    return (unsigned short)r;
}

// ---------------------------------------------------------------------------
// Kernel 1: projections -> bf16.  q,k: [B,N,8]  v: [B,C,N]
// ---------------------------------------------------------------------------
__global__ __launch_bounds__(256) void proj_kernel(
    const float* __restrict__ x,
    const float* __restrict__ wq, const float* __restrict__ bq,
    const float* __restrict__ wk, const float* __restrict__ bk,
    const float* __restrict__ wv, const float* __restrict__ bv,
    unsigned short* __restrict__ qo, unsigned short* __restrict__ ko,
    unsigned short* __restrict__ vo)
{
    const int b = blockIdx.x;
    const int n0 = blockIdx.y * 64;
    const int tid = threadIdx.x;

    __shared__ float xs[64][65];

    const float* xb = x + (size_t)b * NC * NN;
#pragma unroll
    for (int rep = 0; rep < 16; ++rep) {
        int idx = rep * 256 + tid;
        int c = idx >> 6, n = idx & 63;
        xs[c][n] = xb[(size_t)c * NN + n0 + n];
    }
    __syncthreads();

    const int n = tid & 63;
    const int rb = tid >> 6;

#pragma unroll
    for (int t = 0; t < 2; ++t) {
        int r = rb + 4 * t;
        float aq = bq[r], ak = bk[r];
#pragma unroll
        for (int c = 0; c < 64; ++c) {
            float xv = xs[c][n];
            aq = fmaf(wq[r * 64 + c], xv, aq);
            ak = fmaf(wk[r * 64 + c], xv, ak);
        }
        qo[((size_t)b * NN + n0 + n) * NM + r] = f2bf(aq);
        ko[((size_t)b * NN + n0 + n) * NM + r] = f2bf(ak);
    }
#pragma unroll
    for (int s = 0; s < 16; ++s) {
        int r = rb + 4 * s;
        float av = bv[r];
#pragma unroll
        for (int c = 0; c < 64; ++c) av = fmaf(wv[r * 64 + c], xs[c][n], av);
        vo[((size_t)b * NC + r) * NN + n0 + n] = f2bf(av);
    }
}

// ---------------------------------------------------------------------------
// Kernel 2: MFMA flash attention + epilogue.
// Block: 256 thr = 4 waves, each wave owns 16 queries. Grid (B, N/64).
// QK^T: mfma 16x16x32 bf16, K padded 8->32 (lanes 16-63 zero).
// P: C-layout -> LDS -> A-layout.  PV: 8 mfma per 64-j tile.
// ---------------------------------------------------------------------------
#define VS_STRIDE 72
#define PS_STRIDE 72

__global__ __launch_bounds__(256) void attn_mfma_kernel(
    const unsigned short* __restrict__ qo, const unsigned short* __restrict__ ko,
    const unsigned short* __restrict__ vo,
    const float* __restrict__ x, const float* __restrict__ gamma,
    float* __restrict__ out)
{
    const int b = blockIdx.x;
    const int tid = threadIdx.x;
    const int wave = tid >> 6;
    const int lane = tid & 63;
    const int i0 = blockIdx.y * 64 + wave * 16;   // first query row of this wave

    __shared__ unsigned short ks[64 * 8];
    __shared__ unsigned short vs[64 * VS_STRIDE];
    __shared__ unsigned short ps[4][16 * PS_STRIDE];

    // Q fragment (A-layout): lanes 0-15 hold q[i0+lane][0..7]; others zero (K pad)
    short8 qf = {};
    if (lane < 16)
        qf = *(const short8*)(qo + ((size_t)b * NN + i0 + lane) * NM);

    float4v acc[4];
#pragma unroll
    for (int ct = 0; ct < 4; ++ct) acc[ct] = (float4v){0.f, 0.f, 0.f, 0.f};
    float m[4] = {-1e30f, -1e30f, -1e30f, -1e30f};
    float l[4] = {0.f, 0.f, 0.f, 0.f};

    const int c0 = lane & 15;
    const int quad = lane >> 4;

    for (int j0 = 0; j0 < NN; j0 += 64) {
        __syncthreads();
        if (tid < 64)
            *(short8*)&ks[tid * 8] =
                *(const short8*)(ko + ((size_t)b * NN + j0 + tid) * NM);
#pragma unroll
        for (int r = 0; r < 2; ++r) {
            int idx = r * 256 + tid;
            int c = idx >> 3, jq = (idx & 7) * 8;
            *(short8*)&vs[c * VS_STRIDE + jq] =
                *(const short8*)(vo + ((size_t)(b * NC + c)) * NN + j0 + jq);
        }
        __syncthreads();

        // ---- scores S[16 x 64] ----
        float4v s[4];
#pragma unroll
        for (int st = 0; st < 4; ++st) {
            short8 kf = {};
            if (lane < 16)
                kf = *(const short8*)&ks[(st * 16 + lane) * 8];
            float4v z = {0.f, 0.f, 0.f, 0.f};
            s[st] = __builtin_amdgcn_mfma_f32_16x16x32_bf16(qf, kf, z, 0, 0, 0);
        }

        // ---- online softmax ----
        float alpha[4];
#pragma unroll
        for (int reg = 0; reg < 4; ++reg) {
            float v = fmaxf(fmaxf(s[0][reg], s[1][reg]), fmaxf(s[2][reg], s[3][reg]));
            v = fmaxf(v, __shfl_xor(v, 1));
            v = fmaxf(v, __shfl_xor(v, 2));
            v = fmaxf(v, __shfl_xor(v, 4));
            v = fmaxf(v, __shfl_xor(v, 8));
            float mn = fmaxf(m[reg], v);
            alpha[reg] = __expf(m[reg] - mn);
            m[reg] = mn;
        }
#pragma unroll
        for (int ct = 0; ct < 4; ++ct) {
#pragma unroll
            for (int reg = 0; reg < 4; ++reg) acc[ct][reg] *= alpha[reg];
        }

        float psum[4] = {0.f, 0.f, 0.f, 0.f};
#pragma unroll
        for (int st = 0; st < 4; ++st) {
#pragma unroll
            for (int reg = 0; reg < 4; ++reg) {
                float p = __expf(s[st][reg] - m[reg]);
                psum[reg] += p;
                ps[wave][(quad * 4 + reg) * PS_STRIDE + st * 16 + c0] = f2bf(p);
            }
        }
#pragma unroll
        for (int reg = 0; reg < 4; ++reg) {
            float v = psum[reg];
            v += __shfl_xor(v, 1);
            v += __shfl_xor(v, 2);
            v += __shfl_xor(v, 4);
            v += __shfl_xor(v, 8);
            l[reg] = l[reg] * alpha[reg] + v;
        }

        // ---- PV: P (A-layout from LDS) x V (B-layout from LDS) ----
#pragma unroll
        for (int kc = 0; kc < 2; ++kc) {
            short8 pf = *(const short8*)&ps[wave][c0 * PS_STRIDE + kc * 32 + quad * 8];
#pragma unroll
            for (int ct = 0; ct < 4; ++ct) {
                short8 vf = *(const short8*)&vs[(ct * 16 + c0) * VS_STRIDE + kc * 32 + quad * 8];
                acc[ct] = __builtin_amdgcn_mfma_f32_16x16x32_bf16(pf, vf, acc[ct], 0, 0, 0);
            }
        }
    }

    // ---- epilogue: out = x + gamma * O / l ----
    const float g = gamma[0];
    float invl[4];
#pragma unroll
    for (int reg = 0; reg < 4; ++reg) invl[reg] = 1.f / l[reg];
#pragma unroll
    for (int ct = 0; ct < 4; ++ct) {
#pragma unroll
        for (int reg = 0; reg < 4; ++reg) {
            int ch = ct * 16 + c0;
            int i = i0 + quad * 4 + reg;
            size_t idx = ((size_t)(b * NC + ch)) * NN + i;
            out[idx] = x[idx] + g * acc[ct][reg] * invl[reg];
        }
    }
}

// ---------------------------------------------------------------------------
extern "C" void kernel_launch(void* const* d_in, const int* in_sizes, int n_in,
                              void* d_out, int out_size, void* d_ws, size_t ws_size,
                              hipStream_t stream) {
    const float* x     = (const float*)d_in[0];
    const float* wq    = (const float*)d_in[1];
    const float* bq    = (const float*)d_in[2];
    const float* wk    = (const float*)d_in[3];
    const float* bk    = (const float*)d_in[4];
    const float* wv    = (const float*)d_in[5];
    const float* bv    = (const float*)d_in[6];
    const float* gamma = (const float*)d_in[7];
    float* out = (float*)d_out;

    unsigned short* ws = (unsigned short*)d_ws;
    unsigned short* qo = ws;                       // 8*4096*8
    unsigned short* ko = qo + (size_t)NB * NN * NM;
    unsigned short* vo = ko + (size_t)NB * NN * NM; // 8*64*4096

    proj_kernel<<<dim3(NB, NN / 64), 256, 0, stream>>>(x, wq, bq, wk, bk, wv, bv,
                                                       qo, ko, vo);
    attn_mfma_kernel<<<dim3(NB, NN / 64), 256, 0, stream>>>(qo, ko, vo, x, gamma, out);
}